// Round 6
// baseline (159.812 us; speedup 1.0000x reference)
//
#include <hip/hip_runtime.h>

// pred/target (4,4,64,128,128) fp32 -> 16 volumes of 64x128x128.
#define NB 16
#define DD 64
#define HH 128
#define WW 128
#define HW (HH * WW)

constexpr int TROWS = 8;               // h-rows per block (256 thr = 8 rows x 32 strips)
constexpr int NQ = 8;                  // d-octants per volume
constexpr int QP = DD / NQ;            // 8 output planes per octant
constexpr float INV_COUNT = 1.0f / 50331648.0f; // 1/(3*16*64*128*128)

__global__ void zero_out_kernel(float* out) {
    if (threadIdx.x == 0 && blockIdx.x == 0) out[0] = 0.0f;
}

// ---- named-register macros (R3 spill lesson); variadic shims (R4 lesson) ----

#define DIFF4(D, A, B, F)                                                   \
    D.x = (A.x - B.x) * (F); D.y = (A.y - B.y) * (F);                       \
    D.z = (A.z - B.z) * (F); D.w = (A.w - B.w) * (F);

// w-partials for one row, 4-wide strip. RS = [1,2,1] smooth, RW = [-1,0,1].
#define ROWPART(D, LM, RP, RS, RW)                                          \
    RS.x = (LM) + 2.f*D.x + D.y;   RS.y = D.x + 2.f*D.y + D.z;              \
    RS.z = D.y + 2.f*D.z + D.w;    RS.w = D.z + 2.f*D.w + (RP);             \
    RW.x = D.y - (LM);  RW.y = D.z - D.x;                                   \
    RW.z = D.w - D.y;   RW.w = (RP) - D.z;

#define RSET_A pAm, pA0, pAp, tAm, tA0, tAp
#define RSET_B pBm, pB0, pBp, tBm, tB0, tBp

// Issue 6 float4 loads for plane d0+REL into the named register set.
#define PLOAD(...) PLOAD_I(__VA_ARGS__)
#define PLOAD_I(Pm, P0, Pp, Tm, T0, Tp, REL) do {                           \
    const int pc_ = min(max(d0 + (REL), 0), DD - 1);                        \
    const float* pp_ = pred   + nbase + (size_t)pc_ * HW;                   \
    const float* pt_ = target + nbase + (size_t)pc_ * HW;                   \
    Pm = *(const float4*)(pp_ + ro_m);                                      \
    P0 = *(const float4*)(pp_ + ro_0);                                      \
    Pp = *(const float4*)(pp_ + ro_p);                                      \
    Tm = *(const float4*)(pt_ + ro_m);                                      \
    T0 = *(const float4*)(pt_ + ro_0);                                      \
    Tp = *(const float4*)(pt_ + ro_p);                                      \
} while (0)

// Consume one register set: plane partials A/H/W, rolling emit + update.
// Emit for out-plane p-1 uses: d-grad A(p)-A(p-2); h-grad Hs+H(p); w-grad Ws+W(p).
#define PCOMP(...) PCOMP_I(__VA_ARGS__)
#define PCOMP_I(Pm, P0, Pp, Tm, T0, Tp, MD, DOEMIT) do {                    \
    const float fm_ = mr_m * (MD), f0_ = (MD), fp_ = mr_p * (MD);           \
    float4 dm_, dc_, dp_;                                                   \
    DIFF4(dm_, Pm, Tm, fm_)  DIFF4(dc_, P0, T0, f0_)  DIFF4(dp_, Pp, Tp, fp_) \
    const float lmm_ = __shfl_up(dm_.w, 1, 32) * lmask;                     \
    const float rpm_ = __shfl_down(dm_.x, 1, 32) * rmask;                   \
    const float lmc_ = __shfl_up(dc_.w, 1, 32) * lmask;                     \
    const float rpc_ = __shfl_down(dc_.x, 1, 32) * rmask;                   \
    const float lmp_ = __shfl_up(dp_.w, 1, 32) * lmask;                     \
    const float rpp_ = __shfl_down(dp_.x, 1, 32) * rmask;                   \
    float4 sm_, sc_, sp_, wm_, wc_, wp_;                                    \
    ROWPART(dm_, lmm_, rpm_, sm_, wm_)                                      \
    ROWPART(dc_, lmc_, rpc_, sc_, wc_)                                      \
    ROWPART(dp_, lmp_, rpp_, sp_, wp_)                                      \
    float4 An_, Hn_, Wn_;                                                   \
    An_.x = sm_.x + 2.f*sc_.x + sp_.x;  An_.y = sm_.y + 2.f*sc_.y + sp_.y;  \
    An_.z = sm_.z + 2.f*sc_.z + sp_.z;  An_.w = sm_.w + 2.f*sc_.w + sp_.w;  \
    Hn_.x = sp_.x - sm_.x;  Hn_.y = sp_.y - sm_.y;                          \
    Hn_.z = sp_.z - sm_.z;  Hn_.w = sp_.w - sm_.w;                          \
    Wn_.x = wm_.x + 2.f*wc_.x + wp_.x;  Wn_.y = wm_.y + 2.f*wc_.y + wp_.y;  \
    Wn_.z = wm_.z + 2.f*wc_.z + wp_.z;  Wn_.w = wm_.w + 2.f*wc_.w + wp_.w;  \
    if (DOEMIT) {                                                           \
        acc += fabsf(An_.x - Ap2.x) + fabsf(An_.y - Ap2.y)                  \
             + fabsf(An_.z - Ap2.z) + fabsf(An_.w - Ap2.w);                 \
        acc += fabsf(Hs.x + Hn_.x) + fabsf(Hs.y + Hn_.y)                    \
             + fabsf(Hs.z + Hn_.z) + fabsf(Hs.w + Hn_.w);                   \
        acc += fabsf(Ws.x + Wn_.x) + fabsf(Ws.y + Wn_.y)                    \
             + fabsf(Ws.z + Wn_.z) + fabsf(Ws.w + Wn_.w);                   \
    }                                                                       \
    Ap2 = Ap1;  Ap1 = An_;                                                  \
    Hs.x = Hp.x + 2.f*Hn_.x;  Hs.y = Hp.y + 2.f*Hn_.y;                      \
    Hs.z = Hp.z + 2.f*Hn_.z;  Hs.w = Hp.w + 2.f*Hn_.w;                      \
    Hp = Hn_;                                                               \
    Ws.x = Wp.x + 2.f*Wn_.x;  Ws.y = Wp.y + 2.f*Wn_.y;                      \
    Ws.z = Wp.z + 2.f*Wn_.z;  Ws.w = Wp.w + 2.f*Wn_.w;                      \
    Wp = Wn_;                                                               \
} while (0)

__global__ __launch_bounds__(256, 4) void sobel_l1_kernel(
    const float* __restrict__ pred,
    const float* __restrict__ target,
    float* __restrict__ out)
{
    __shared__ float wsum[4];          // only LDS use: final block reduction

    const int tid = threadIdx.x;
    int b = blockIdx.x;                // 2048 blocks: 16 bh x 8 oct x 16 vol
    const int bh = b & 15; b >>= 4;
    const int q  = b & 7;  b >>= 3;
    const int bn = b;

    const int row = tid >> 5;          // 0..7
    const int sc  = tid & 31;          // 32 strips of 4 floats
    const int gh  = bh * TROWS + row;
    const int d0  = q * QP;
    const size_t nbase = (size_t)bn * (size_t)(DD * HW);

    const int wq   = sc * 4;
    const int ro_m = max(gh - 1, 0) * WW + wq;      // clamped addr, zeroed by mask
    const int ro_0 = gh * WW + wq;
    const int ro_p = min(gh + 1, HH - 1) * WW + wq;
    const float mr_m = (gh >= 1) ? 1.f : 0.f;       // h zero-pad masks
    const float mr_p = (gh + 1 < HH) ? 1.f : 0.f;
    const float lmask = (sc == 0)  ? 0.f : 1.f;     // w zero-pad masks
    const float rmask = (sc == 31) ? 0.f : 1.f;
    const float mdA = (q == 0)      ? 0.f : 1.f;    // d zero-pad masks
    const float mdB = (q == NQ - 1) ? 0.f : 1.f;

    // two in-flight load sets (ping-pong) + rolling second-order state
    float4 pAm, pA0, pAp, tAm, tA0, tAp;
    float4 pBm, pB0, pBp, tBm, tB0, tBp;
    const float4 z4 = float4{0.f, 0.f, 0.f, 0.f};
    float4 Ap1 = z4, Ap2 = z4, Hs = z4, Hp = z4, Ws = z4, Wp = z4;
    float acc = 0.f;

    // 10 plane steps; every PCOMP runs with the OTHER set's 6 loads in flight.
    PLOAD(RSET_A, -1);
    PLOAD(RSET_B,  0);
    PCOMP(RSET_A, mdA, false);         // plane -1
    PLOAD(RSET_A,  1);
    PCOMP(RSET_B, 1.f, false);         // plane 0
    PLOAD(RSET_B,  2);
    PCOMP(RSET_A, 1.f, true);          // plane 1 -> out d0+0
    PLOAD(RSET_A,  3);
    PCOMP(RSET_B, 1.f, true);          // out d0+1
    PLOAD(RSET_B,  4);
    PCOMP(RSET_A, 1.f, true);          // out d0+2
    PLOAD(RSET_A,  5);
    PCOMP(RSET_B, 1.f, true);          // out d0+3
    PLOAD(RSET_B,  6);
    PCOMP(RSET_A, 1.f, true);          // out d0+4
    PLOAD(RSET_A,  7);
    PCOMP(RSET_B, 1.f, true);          // out d0+5
    PLOAD(RSET_B,  8);
    PCOMP(RSET_A, 1.f, true);          // out d0+6
    PCOMP(RSET_B, mdB, true);          // plane 8 -> out d0+7

    // ---- block reduction ----
#pragma unroll
    for (int off = 32; off > 0; off >>= 1)
        acc += __shfl_down(acc, off, 64);
    if ((tid & 63) == 0) wsum[tid >> 6] = acc;
    __syncthreads();
    if (tid == 0) {
        const float s = wsum[0] + wsum[1] + wsum[2] + wsum[3];
        atomicAdd(out, s * INV_COUNT);
    }
}

extern "C" void kernel_launch(void* const* d_in, const int* in_sizes, int n_in,
                              void* d_out, int out_size, void* d_ws, size_t ws_size,
                              hipStream_t stream) {
    const float* pred   = (const float*)d_in[0];
    const float* target = (const float*)d_in[1];
    float* out = (float*)d_out;

    zero_out_kernel<<<1, 64, 0, stream>>>(out);

    // 16 volumes * 8 d-octants * 16 h-tiles = 2048 blocks
    const int nblocks = NB * NQ * (HH / TROWS);
    sobel_l1_kernel<<<nblocks, 256, 0, stream>>>(pred, target, out);
}

// Round 7
// 149.910 us; speedup vs baseline: 1.0661x; 1.0661x over previous
//
#include <hip/hip_runtime.h>

// pred/target (4,4,64,128,128) fp32 -> 16 volumes of 64x128x128.
#define NB 16
#define DD 64
#define HH 128
#define WW 128
#define HW (HH * WW)

constexpr int TROWS = 8;               // h-rows per block (256 thr = 8 rows x 32 strips)
constexpr int NQ = 8;                  // d-octants per volume
constexpr int QP = DD / NQ;            // 8 output planes per octant
constexpr float INV_COUNT = 1.0f / 50331648.0f; // 1/(3*16*64*128*128)

typedef float fl4 __attribute__((ext_vector_type(4)));  // asm-friendly 16B vector

__global__ void zero_out_kernel(float* out) {
    if (threadIdx.x == 0 && blockIdx.x == 0) out[0] = 0.0f;
}

// ---- named-register macros (R3 lesson); variadic shims (R4 lesson);
// ---- asm loads + counted vmcnt + sched_barrier (R6 lesson: compiler
// ---- re-serializes C++ ping-pong; asm-volatile order it cannot undo).

#define DIFF4(D, A, B, F)                                                   \
    D.x = (A.x - B.x) * (F); D.y = (A.y - B.y) * (F);                       \
    D.z = (A.z - B.z) * (F); D.w = (A.w - B.w) * (F);

// w-partials for one row, 4-wide strip. RS = [1,2,1] smooth, RW = [-1,0,1].
#define ROWPART(D, LM, RP, RS, RW)                                          \
    RS.x = (LM) + 2.f*D.x + D.y;   RS.y = D.x + 2.f*D.y + D.z;              \
    RS.z = D.y + 2.f*D.z + D.w;    RS.w = D.z + 2.f*D.w + (RP);             \
    RW.x = D.y - (LM);  RW.y = D.z - D.x;                                   \
    RW.z = D.w - D.y;   RW.w = (RP) - D.z;

#define RSET_A pAm, pA0, pAp, tAm, tA0, tAp
#define RSET_B pBm, pB0, pBp, tBm, tB0, tBp

#define SB __builtin_amdgcn_sched_barrier(0)
#define VW6 { asm volatile("s_waitcnt vmcnt(6)" ::: "memory"); SB; }
#define VW0 { asm volatile("s_waitcnt vmcnt(0)" ::: "memory"); SB; }

// Issue 6 asm global_load_dwordx4 for plane d0+REL into the named set.
// asm volatile: issue order is fixed; results unusable until our waitcnt.
#define GLOAD(...) GLOAD_I(__VA_ARGS__)
#define GLOAD_I(Pm, P0, Pp, Tm, T0, Tp, REL) do {                           \
    const int pc_ = min(max(d0 + (REL), 0), DD - 1);                        \
    const float* pp_ = pred   + nbase + (size_t)pc_ * HW;                   \
    const float* pt_ = target + nbase + (size_t)pc_ * HW;                   \
    asm volatile("global_load_dwordx4 %0, %1, off" : "=v"(Pm) : "v"(pp_ + ro_m)); \
    asm volatile("global_load_dwordx4 %0, %1, off" : "=v"(P0) : "v"(pp_ + ro_0)); \
    asm volatile("global_load_dwordx4 %0, %1, off" : "=v"(Pp) : "v"(pp_ + ro_p)); \
    asm volatile("global_load_dwordx4 %0, %1, off" : "=v"(Tm) : "v"(pt_ + ro_m)); \
    asm volatile("global_load_dwordx4 %0, %1, off" : "=v"(T0) : "v"(pt_ + ro_0)); \
    asm volatile("global_load_dwordx4 %0, %1, off" : "=v"(Tp) : "v"(pt_ + ro_p)); \
} while (0)

// Consume one register set: plane partials A/H/W, rolling emit + update.
// Emit for out-plane p-1 uses: d-grad A(p)-A(p-2); h-grad Hs+H(p); w-grad Ws+W(p).
#define PCOMP(...) PCOMP_I(__VA_ARGS__)
#define PCOMP_I(Pm, P0, Pp, Tm, T0, Tp, MD, DOEMIT) do {                    \
    const float fm_ = mr_m * (MD), f0_ = (MD), fp_ = mr_p * (MD);           \
    fl4 dm_, dc_, dp_;                                                      \
    DIFF4(dm_, Pm, Tm, fm_)  DIFF4(dc_, P0, T0, f0_)  DIFF4(dp_, Pp, Tp, fp_) \
    const float lmm_ = __shfl_up(dm_.w, 1, 32) * lmask;                     \
    const float rpm_ = __shfl_down(dm_.x, 1, 32) * rmask;                   \
    const float lmc_ = __shfl_up(dc_.w, 1, 32) * lmask;                     \
    const float rpc_ = __shfl_down(dc_.x, 1, 32) * rmask;                   \
    const float lmp_ = __shfl_up(dp_.w, 1, 32) * lmask;                     \
    const float rpp_ = __shfl_down(dp_.x, 1, 32) * rmask;                   \
    fl4 sm_, sc_, sp_, wm_, wc_, wp_;                                       \
    ROWPART(dm_, lmm_, rpm_, sm_, wm_)                                      \
    ROWPART(dc_, lmc_, rpc_, sc_, wc_)                                      \
    ROWPART(dp_, lmp_, rpp_, sp_, wp_)                                      \
    fl4 An_, Hn_, Wn_;                                                      \
    An_.x = sm_.x + 2.f*sc_.x + sp_.x;  An_.y = sm_.y + 2.f*sc_.y + sp_.y;  \
    An_.z = sm_.z + 2.f*sc_.z + sp_.z;  An_.w = sm_.w + 2.f*sc_.w + sp_.w;  \
    Hn_.x = sp_.x - sm_.x;  Hn_.y = sp_.y - sm_.y;                          \
    Hn_.z = sp_.z - sm_.z;  Hn_.w = sp_.w - sm_.w;                          \
    Wn_.x = wm_.x + 2.f*wc_.x + wp_.x;  Wn_.y = wm_.y + 2.f*wc_.y + wp_.y;  \
    Wn_.z = wm_.z + 2.f*wc_.z + wp_.z;  Wn_.w = wm_.w + 2.f*wc_.w + wp_.w;  \
    if (DOEMIT) {                                                           \
        acc += fabsf(An_.x - Ap2.x) + fabsf(An_.y - Ap2.y)                  \
             + fabsf(An_.z - Ap2.z) + fabsf(An_.w - Ap2.w);                 \
        acc += fabsf(Hs.x + Hn_.x) + fabsf(Hs.y + Hn_.y)                    \
             + fabsf(Hs.z + Hn_.z) + fabsf(Hs.w + Hn_.w);                   \
        acc += fabsf(Ws.x + Wn_.x) + fabsf(Ws.y + Wn_.y)                    \
             + fabsf(Ws.z + Wn_.z) + fabsf(Ws.w + Wn_.w);                   \
    }                                                                       \
    Ap2 = Ap1;  Ap1 = An_;                                                  \
    Hs.x = Hp.x + 2.f*Hn_.x;  Hs.y = Hp.y + 2.f*Hn_.y;                      \
    Hs.z = Hp.z + 2.f*Hn_.z;  Hs.w = Hp.w + 2.f*Hn_.w;                      \
    Hp = Hn_;                                                               \
    Ws.x = Wp.x + 2.f*Wn_.x;  Ws.y = Wp.y + 2.f*Wn_.y;                      \
    Ws.z = Wp.z + 2.f*Wn_.z;  Ws.w = Wp.w + 2.f*Wn_.w;                      \
    Wp = Wn_;                                                               \
} while (0)

__global__ __launch_bounds__(256, 3) void sobel_l1_kernel(
    const float* __restrict__ pred,
    const float* __restrict__ target,
    float* __restrict__ out)
{
    __shared__ float wsum[4];          // only LDS use: final block reduction

    const int tid = threadIdx.x;
    int b = blockIdx.x;                // 2048 blocks: 16 bh x 8 oct x 16 vol
    const int bh = b & 15; b >>= 4;
    const int q  = b & 7;  b >>= 3;
    const int bn = b;

    const int row = tid >> 5;          // 0..7
    const int sc  = tid & 31;          // 32 strips of 4 floats
    const int gh  = bh * TROWS + row;
    const int d0  = q * QP;
    const size_t nbase = (size_t)bn * (size_t)(DD * HW);

    const int wq   = sc * 4;
    const int ro_m = max(gh - 1, 0) * WW + wq;      // clamped addr, zeroed by mask
    const int ro_0 = gh * WW + wq;
    const int ro_p = min(gh + 1, HH - 1) * WW + wq;
    const float mr_m = (gh >= 1) ? 1.f : 0.f;       // h zero-pad masks
    const float mr_p = (gh + 1 < HH) ? 1.f : 0.f;
    const float lmask = (sc == 0)  ? 0.f : 1.f;     // w zero-pad masks
    const float rmask = (sc == 31) ? 0.f : 1.f;
    const float mdA = (q == 0)      ? 0.f : 1.f;    // d zero-pad masks
    const float mdB = (q == NQ - 1) ? 0.f : 1.f;

    // two in-flight load sets (ping-pong) + rolling second-order state
    fl4 pAm, pA0, pAp, tAm, tA0, tAp;
    fl4 pBm, pB0, pBp, tBm, tB0, tBp;
    fl4 Ap1 = {0.f,0.f,0.f,0.f}, Ap2 = {0.f,0.f,0.f,0.f};
    fl4 Hs  = {0.f,0.f,0.f,0.f}, Hp  = {0.f,0.f,0.f,0.f};
    fl4 Ws  = {0.f,0.f,0.f,0.f}, Wp  = {0.f,0.f,0.f,0.f};
    float acc = 0.f;

    // Steady state: 12 loads outstanding; vmcnt(6) waits only for the
    // older set. sched_barrier(0) pins compute strictly between its
    // waitcnt and the next issue (also enforces use-before-redefine).
    GLOAD(RSET_A, -1);
    GLOAD(RSET_B,  0);
    VW6; PCOMP(RSET_A, mdA, false); SB;    // plane -1
    GLOAD(RSET_A,  1);
    VW6; PCOMP(RSET_B, 1.f, false); SB;    // plane 0
    GLOAD(RSET_B,  2);
    VW6; PCOMP(RSET_A, 1.f, true);  SB;    // plane 1 -> out d0+0
    GLOAD(RSET_A,  3);
    VW6; PCOMP(RSET_B, 1.f, true);  SB;    // out d0+1
    GLOAD(RSET_B,  4);
    VW6; PCOMP(RSET_A, 1.f, true);  SB;    // out d0+2
    GLOAD(RSET_A,  5);
    VW6; PCOMP(RSET_B, 1.f, true);  SB;    // out d0+3
    GLOAD(RSET_B,  6);
    VW6; PCOMP(RSET_A, 1.f, true);  SB;    // out d0+4
    GLOAD(RSET_A,  7);
    VW6; PCOMP(RSET_B, 1.f, true);  SB;    // out d0+5
    GLOAD(RSET_B,  8);
    VW6; PCOMP(RSET_A, 1.f, true);  SB;    // out d0+6
    VW0; PCOMP(RSET_B, mdB, true);         // plane 8 -> out d0+7

    // ---- block reduction ----
#pragma unroll
    for (int off = 32; off > 0; off >>= 1)
        acc += __shfl_down(acc, off, 64);
    if ((tid & 63) == 0) wsum[tid >> 6] = acc;
    __syncthreads();
    if (tid == 0) {
        const float s = wsum[0] + wsum[1] + wsum[2] + wsum[3];
        atomicAdd(out, s * INV_COUNT);
    }
}

extern "C" void kernel_launch(void* const* d_in, const int* in_sizes, int n_in,
                              void* d_out, int out_size, void* d_ws, size_t ws_size,
                              hipStream_t stream) {
    const float* pred   = (const float*)d_in[0];
    const float* target = (const float*)d_in[1];
    float* out = (float*)d_out;

    zero_out_kernel<<<1, 64, 0, stream>>>(out);

    // 16 volumes * 8 d-octants * 16 h-tiles = 2048 blocks
    const int nblocks = NB * NQ * (HH / TROWS);
    sobel_l1_kernel<<<nblocks, 256, 0, stream>>>(pred, target, out);
}

// Round 8
// 144.678 us; speedup vs baseline: 1.1046x; 1.0362x over previous
//
#include <hip/hip_runtime.h>

// pred/target (4,4,64,128,128) fp32 -> 16 volumes of 64x128x128.
#define NB 16
#define DD 64
#define HH 128
#define WW 128
#define HW (HH * WW)

constexpr int TROWS = 8;               // h-rows per block (256 thr = 8 rows x 32 strips)
constexpr int NQ = 8;                  // d-octants per volume
constexpr int QP = DD / NQ;            // 8 output planes per octant
constexpr float INV_COUNT = 1.0f / 50331648.0f; // 1/(3*16*64*128*128)

typedef float fl4 __attribute__((ext_vector_type(4)));  // asm-friendly 16B vector

__global__ void zero_out_kernel(float* out) {
    if (threadIdx.x == 0 && blockIdx.x == 0) out[0] = 0.0f;
}

// ---- named-register macros (R3 lesson); variadic shims (R4 lesson);
// ---- asm loads + counted vmcnt + sched_barrier (R6/R7 lesson: the
// ---- counted-vmcnt pipeline is the only lever that moved duration;
// ---- R8: deepen it 2 -> 4 sets so vmcnt(18) tolerates ~3 compute
// ---- phases (~900 cyc) of fill latency, matching HBM worst case).

#define DIFF4(D, A, B, F)                                                   \
    D.x = (A.x - B.x) * (F); D.y = (A.y - B.y) * (F);                       \
    D.z = (A.z - B.z) * (F); D.w = (A.w - B.w) * (F);

// w-partials for one row, 4-wide strip. RS = [1,2,1] smooth, RW = [-1,0,1].
#define ROWPART(D, LM, RP, RS, RW)                                          \
    RS.x = (LM) + 2.f*D.x + D.y;   RS.y = D.x + 2.f*D.y + D.z;              \
    RS.z = D.y + 2.f*D.z + D.w;    RS.w = D.z + 2.f*D.w + (RP);             \
    RW.x = D.y - (LM);  RW.y = D.z - D.x;                                   \
    RW.z = D.w - D.y;   RW.w = (RP) - D.z;

#define RSET_A pAm, pA0, pAp, tAm, tA0, tAp
#define RSET_B pBm, pB0, pBp, tBm, tB0, tBp
#define RSET_C pCm, pC0, pCp, tCm, tC0, tCp
#define RSET_D pDm, pD0, pDp, tDm, tD0, tDp

#define SB __builtin_amdgcn_sched_barrier(0)
#define VW18 { asm volatile("s_waitcnt vmcnt(18)" ::: "memory"); SB; }
#define VW12 { asm volatile("s_waitcnt vmcnt(12)" ::: "memory"); SB; }
#define VW6  { asm volatile("s_waitcnt vmcnt(6)"  ::: "memory"); SB; }
#define VW0  { asm volatile("s_waitcnt vmcnt(0)"  ::: "memory"); SB; }

// Issue 6 asm global_load_dwordx4 for plane d0+REL into the named set.
// asm volatile: issue order is fixed; results unusable until our waitcnt.
#define GLOAD(...) GLOAD_I(__VA_ARGS__)
#define GLOAD_I(Pm, P0, Pp, Tm, T0, Tp, REL) do {                           \
    const int pc_ = min(max(d0 + (REL), 0), DD - 1);                        \
    const float* pp_ = pred   + nbase + (size_t)pc_ * HW;                   \
    const float* pt_ = target + nbase + (size_t)pc_ * HW;                   \
    asm volatile("global_load_dwordx4 %0, %1, off" : "=v"(Pm) : "v"(pp_ + ro_m)); \
    asm volatile("global_load_dwordx4 %0, %1, off" : "=v"(P0) : "v"(pp_ + ro_0)); \
    asm volatile("global_load_dwordx4 %0, %1, off" : "=v"(Pp) : "v"(pp_ + ro_p)); \
    asm volatile("global_load_dwordx4 %0, %1, off" : "=v"(Tm) : "v"(pt_ + ro_m)); \
    asm volatile("global_load_dwordx4 %0, %1, off" : "=v"(T0) : "v"(pt_ + ro_0)); \
    asm volatile("global_load_dwordx4 %0, %1, off" : "=v"(Tp) : "v"(pt_ + ro_p)); \
} while (0)

// Consume one register set: plane partials A/H/W, rolling emit + update.
// Emit for out-plane p-1 uses: d-grad A(p)-A(p-2); h-grad Hs+H(p); w-grad Ws+W(p).
#define PCOMP(...) PCOMP_I(__VA_ARGS__)
#define PCOMP_I(Pm, P0, Pp, Tm, T0, Tp, MD, DOEMIT) do {                    \
    const float fm_ = mr_m * (MD), f0_ = (MD), fp_ = mr_p * (MD);           \
    fl4 dm_, dc_, dp_;                                                      \
    DIFF4(dm_, Pm, Tm, fm_)  DIFF4(dc_, P0, T0, f0_)  DIFF4(dp_, Pp, Tp, fp_) \
    const float lmm_ = __shfl_up(dm_.w, 1, 32) * lmask;                     \
    const float rpm_ = __shfl_down(dm_.x, 1, 32) * rmask;                   \
    const float lmc_ = __shfl_up(dc_.w, 1, 32) * lmask;                     \
    const float rpc_ = __shfl_down(dc_.x, 1, 32) * rmask;                   \
    const float lmp_ = __shfl_up(dp_.w, 1, 32) * lmask;                     \
    const float rpp_ = __shfl_down(dp_.x, 1, 32) * rmask;                   \
    fl4 sm_, sc_, sp_, wm_, wc_, wp_;                                       \
    ROWPART(dm_, lmm_, rpm_, sm_, wm_)                                      \
    ROWPART(dc_, lmc_, rpc_, sc_, wc_)                                      \
    ROWPART(dp_, lmp_, rpp_, sp_, wp_)                                      \
    fl4 An_, Hn_, Wn_;                                                      \
    An_.x = sm_.x + 2.f*sc_.x + sp_.x;  An_.y = sm_.y + 2.f*sc_.y + sp_.y;  \
    An_.z = sm_.z + 2.f*sc_.z + sp_.z;  An_.w = sm_.w + 2.f*sc_.w + sp_.w;  \
    Hn_.x = sp_.x - sm_.x;  Hn_.y = sp_.y - sm_.y;                          \
    Hn_.z = sp_.z - sm_.z;  Hn_.w = sp_.w - sm_.w;                          \
    Wn_.x = wm_.x + 2.f*wc_.x + wp_.x;  Wn_.y = wm_.y + 2.f*wc_.y + wp_.y;  \
    Wn_.z = wm_.z + 2.f*wc_.z + wp_.z;  Wn_.w = wm_.w + 2.f*wc_.w + wp_.w;  \
    if (DOEMIT) {                                                           \
        acc += fabsf(An_.x - Ap2.x) + fabsf(An_.y - Ap2.y)                  \
             + fabsf(An_.z - Ap2.z) + fabsf(An_.w - Ap2.w);                 \
        acc += fabsf(Hs.x + Hn_.x) + fabsf(Hs.y + Hn_.y)                    \
             + fabsf(Hs.z + Hn_.z) + fabsf(Hs.w + Hn_.w);                   \
        acc += fabsf(Ws.x + Wn_.x) + fabsf(Ws.y + Wn_.y)                    \
             + fabsf(Ws.z + Wn_.z) + fabsf(Ws.w + Wn_.w);                   \
    }                                                                       \
    Ap2 = Ap1;  Ap1 = An_;                                                  \
    Hs.x = Hp.x + 2.f*Hn_.x;  Hs.y = Hp.y + 2.f*Hn_.y;                      \
    Hs.z = Hp.z + 2.f*Hn_.z;  Hs.w = Hp.w + 2.f*Hn_.w;                      \
    Hp = Hn_;                                                               \
    Ws.x = Wp.x + 2.f*Wn_.x;  Ws.y = Wp.y + 2.f*Wn_.y;                      \
    Ws.z = Wp.z + 2.f*Wn_.z;  Ws.w = Wp.w + 2.f*Wn_.w;                      \
    Wp = Wn_;                                                               \
} while (0)

__global__ __launch_bounds__(256, 3) void sobel_l1_kernel(
    const float* __restrict__ pred,
    const float* __restrict__ target,
    float* __restrict__ out)
{
    __shared__ float wsum[4];          // only LDS use: final block reduction

    const int tid = threadIdx.x;
    int b = blockIdx.x;                // 2048 blocks: 16 bh x 8 oct x 16 vol
    const int bh = b & 15; b >>= 4;
    const int q  = b & 7;  b >>= 3;
    const int bn = b;

    const int row = tid >> 5;          // 0..7
    const int sc  = tid & 31;          // 32 strips of 4 floats
    const int gh  = bh * TROWS + row;
    const int d0  = q * QP;
    const size_t nbase = (size_t)bn * (size_t)(DD * HW);

    const int wq   = sc * 4;
    const int ro_m = max(gh - 1, 0) * WW + wq;      // clamped addr, zeroed by mask
    const int ro_0 = gh * WW + wq;
    const int ro_p = min(gh + 1, HH - 1) * WW + wq;
    const float mr_m = (gh >= 1) ? 1.f : 0.f;       // h zero-pad masks
    const float mr_p = (gh + 1 < HH) ? 1.f : 0.f;
    const float lmask = (sc == 0)  ? 0.f : 1.f;     // w zero-pad masks
    const float rmask = (sc == 31) ? 0.f : 1.f;
    const float mdA = (q == 0)      ? 0.f : 1.f;    // d zero-pad masks
    const float mdB = (q == NQ - 1) ? 0.f : 1.f;

    // four in-flight load sets (depth-4 pipeline) + rolling state
    fl4 pAm, pA0, pAp, tAm, tA0, tAp;
    fl4 pBm, pB0, pBp, tBm, tB0, tBp;
    fl4 pCm, pC0, pCp, tCm, tC0, tCp;
    fl4 pDm, pD0, pDp, tDm, tD0, tDp;
    fl4 Ap1 = {0.f,0.f,0.f,0.f}, Ap2 = {0.f,0.f,0.f,0.f};
    fl4 Hs  = {0.f,0.f,0.f,0.f}, Hp  = {0.f,0.f,0.f,0.f};
    fl4 Ws  = {0.f,0.f,0.f,0.f}, Wp  = {0.f,0.f,0.f,0.f};
    float acc = 0.f;

    // Steady state: 24 loads outstanding; vmcnt(18) waits only for the
    // oldest set (3 compute phases of latency tolerance). sched_barrier(0)
    // pins compute strictly between its waitcnt and the next issue.
    GLOAD(RSET_A, -1);
    GLOAD(RSET_B,  0);
    GLOAD(RSET_C,  1);
    GLOAD(RSET_D,  2);
    VW18; PCOMP(RSET_A, mdA, false); SB; GLOAD(RSET_A, 3);  // plane -1
    VW18; PCOMP(RSET_B, 1.f, false); SB; GLOAD(RSET_B, 4);  // plane 0
    VW18; PCOMP(RSET_C, 1.f, true);  SB; GLOAD(RSET_C, 5);  // out d0+0
    VW18; PCOMP(RSET_D, 1.f, true);  SB; GLOAD(RSET_D, 6);  // out d0+1
    VW18; PCOMP(RSET_A, 1.f, true);  SB; GLOAD(RSET_A, 7);  // out d0+2
    VW18; PCOMP(RSET_B, 1.f, true);  SB; GLOAD(RSET_B, 8);  // out d0+3
    VW18; PCOMP(RSET_C, 1.f, true);  SB;                    // out d0+4
    VW12; PCOMP(RSET_D, 1.f, true);  SB;                    // out d0+5
    VW6;  PCOMP(RSET_A, 1.f, true);  SB;                    // out d0+6
    VW0;  PCOMP(RSET_B, mdB, true);                         // out d0+7

    // ---- block reduction ----
#pragma unroll
    for (int off = 32; off > 0; off >>= 1)
        acc += __shfl_down(acc, off, 64);
    if ((tid & 63) == 0) wsum[tid >> 6] = acc;
    __syncthreads();
    if (tid == 0) {
        const float s = wsum[0] + wsum[1] + wsum[2] + wsum[3];
        atomicAdd(out, s * INV_COUNT);
    }
}

extern "C" void kernel_launch(void* const* d_in, const int* in_sizes, int n_in,
                              void* d_out, int out_size, void* d_ws, size_t ws_size,
                              hipStream_t stream) {
    const float* pred   = (const float*)d_in[0];
    const float* target = (const float*)d_in[1];
    float* out = (float*)d_out;

    zero_out_kernel<<<1, 64, 0, stream>>>(out);

    // 16 volumes * 8 d-octants * 16 h-tiles = 2048 blocks
    const int nblocks = NB * NQ * (HH / TROWS);
    sobel_l1_kernel<<<nblocks, 256, 0, stream>>>(pred, target, out);
}